// Round 9
// baseline (82.335 us; speedup 1.0000x reference)
//
#include <hip/hip_runtime.h>
#include <hip/hip_bf16.h>

typedef __bf16 bf16x8 __attribute__((ext_vector_type(8)));
typedef float f32x4 __attribute__((ext_vector_type(4)));
typedef float f32x16 __attribute__((ext_vector_type(16)));
typedef unsigned int u32x2 __attribute__((ext_vector_type(2)));
typedef unsigned int u32x4 __attribute__((ext_vector_type(4)));
typedef unsigned short us8 __attribute__((ext_vector_type(8)));

#define MFMA32(a, b, c) __builtin_amdgcn_mfma_f32_32x32x16_bf16((a), (b), (c), 0, 0, 0)

// ---- constants ----
#define BATCH 8
#define SEQ 512
#define HID 768
#define NHEAD 12
#define HDIM 64

__device__ __forceinline__ unsigned short f2bf(float f) {
    unsigned int u = __float_as_uint(f);
    u += 0x7fffu + ((u >> 16) & 1u);
    return (unsigned short)(u >> 16);
}

__device__ __forceinline__ unsigned int cvtpk_bf16(float lo, float hi) {
    unsigned int r;
    asm("v_cvt_pk_bf16_f32 %0, %1, %2" : "=v"(r) : "v"(lo), "v"(hi));
    return r;
}

// ---- fused fp32 -> bf16 convert INTO MFMA-FRAGMENT-TILED layout ----
// frag(t, kt) = 1024 contiguous bytes: lane l's 8 bf16 at l*16B covering
// (row = l&31, k = kt*16 + (l>>5)*8 + j).  A-frags: t = mt in [0,128);
// B-frags: t = nt in [0,72) over concatenated Wq|Wk|Wv rows. 48 kt per t.
// Each thread converts 8 consecutive k of one row -> exactly one 16B slot.
__global__ __launch_bounds__(256) void cvt_all_kernel(const float4* __restrict__ hs,
                                                      const float4* __restrict__ Wq,
                                                      const float4* __restrict__ Wk,
                                                      const float4* __restrict__ Wv,
                                                      unsigned short* __restrict__ hsb,
                                                      unsigned short* __restrict__ wb) {
    int i = blockIdx.x * 256 + threadIdx.x;   // chunk-of-8-floats index
    float4 v0, v1;
    unsigned short* dst;
    size_t uidx;
    if (i < 393216) {                         // hidden: 4096 rows x 96 chunks
        int m = i / 96, cc = i - (i / 96) * 96;
        v0 = hs[2 * i];
        v1 = hs[2 * i + 1];
        uidx = ((size_t)((m >> 5) * 48 + (cc >> 1))) * 512 + (((cc & 1) << 5) + (m & 31)) * 8;
        dst = hsb;
    } else {                                  // weights: 3 x 768 rows x 96 chunks
        int j = i - 393216;
        int which = j / 73728;
        int jj = j - which * 73728;
        int n = jj / 96, cc = jj - (jj / 96) * 96;
        const float4* src = (which == 0) ? Wq : ((which == 1) ? Wk : Wv);
        v0 = src[2 * jj];
        v1 = src[2 * jj + 1];
        int nt = which * 24 + (n >> 5);
        uidx = ((size_t)(nt * 48 + (cc >> 1))) * 512 + (((cc & 1) << 5) + (n & 31)) * 8;
        dst = wb;
    }
    us8 o;
    o[0] = f2bf(v0.x); o[1] = f2bf(v0.y); o[2] = f2bf(v0.z); o[3] = f2bf(v0.w);
    o[4] = f2bf(v1.x); o[5] = f2bf(v1.y); o[6] = f2bf(v1.z); o[7] = f2bf(v1.w);
    *reinterpret_cast<us8*>(dst + uidx) = o;
}

// ---- fused QKV GEMM v5: barrier-free, LDS-free, fragment-tiled coalesced loads ----
// One wave per 64x64 output tile; 2x2 mfma_32x32x16 accs; 48 K-steps of
// {4 x 1KB-coalesced loads + 4 MFMA32}. Grid 2304, 16Mt x 18Nt per XCD (3.2MB L2).
__global__ __launch_bounds__(64) void qkv_gemm_kernel(const unsigned short* __restrict__ hsb,
                                                      const unsigned short* __restrict__ wb,
                                                      const float* __restrict__ bq,
                                                      const float* __restrict__ bk,
                                                      const float* __restrict__ bv,
                                                      unsigned short* __restrict__ Qb,
                                                      unsigned short* __restrict__ Kb,
                                                      unsigned short* __restrict__ VTb) {
    const int l = threadIdx.x;
    const int lq = l & 31, h5 = l >> 5;

    const int id = blockIdx.x;            // 0..2303
    const int xcd = id & 7, j = id >> 3;  // j in [0,288) = 16 x 18
    const int tm = (xcd >> 1) * 16 + j / 18;   // 0..63
    const int tn = (xcd & 1) * 18 + j % 18;    // 0..35

    // fragment pointers (ushort units); each kt advances 512 ushorts = 1KB
    const unsigned short* pa0 = hsb + (size_t)(tm * 2) * 48 * 512 + l * 8;
    const unsigned short* pa1 = pa0 + 48 * 512;
    const unsigned short* pb0 = wb + (size_t)(tn * 2) * 48 * 512 + l * 8;
    const unsigned short* pb1 = pb0 + 48 * 512;

    f32x16 acc00 = {}, acc01 = {}, acc10 = {}, acc11 = {};

#pragma unroll 4
    for (int kt = 0; kt < 48; ++kt) {
        bf16x8 a0 = *reinterpret_cast<const bf16x8*>(pa0 + kt * 512);
        bf16x8 a1 = *reinterpret_cast<const bf16x8*>(pa1 + kt * 512);
        bf16x8 b0 = *reinterpret_cast<const bf16x8*>(pb0 + kt * 512);
        bf16x8 b1 = *reinterpret_cast<const bf16x8*>(pb1 + kt * 512);
        acc00 = MFMA32(a0, b0, acc00);
        acc01 = MFMA32(a0, b1, acc01);
        acc10 = MFMA32(a1, b0, acc10);
        acc11 = MFMA32(a1, b1, acc11);
    }

    // epilogue (R7-verified mapping): C/D col = lq, row = (r&3) + 8*(r>>2) + 4*h5
    f32x16 accs[2][2] = {{acc00, acc01}, {acc10, acc11}};
#pragma unroll
    for (int ni = 0; ni < 2; ++ni) {
        int col = tn * 64 + ni * 32 + lq;         // 0..2303
        int which = col / HID;                    // 0=Q 1=K 2=V
        int oo = col - which * HID;
        int head = oo >> 6, d = oo & 63;
        const float* bias = (which == 0) ? bq : ((which == 1) ? bk : bv);
        float bvv = bias[oo];
#pragma unroll
        for (int mi = 0; mi < 2; ++mi) {
            f32x16 a = accs[mi][ni];
#pragma unroll
            for (int g = 0; g < 4; ++g) {
                int row0 = tm * 64 + mi * 32 + 8 * g + 4 * h5;   // 4-aligned
                int bi = row0 >> 9;
                int s0 = row0 & 511;
                if (which == 2) {
                    ushort4 pk;
                    pk.x = f2bf(a[4 * g + 0] + bvv);
                    pk.y = f2bf(a[4 * g + 1] + bvv);
                    pk.z = f2bf(a[4 * g + 2] + bvv);
                    pk.w = f2bf(a[4 * g + 3] + bvv);
                    *reinterpret_cast<ushort4*>(
                        &VTb[((size_t)(bi * NHEAD + head) * HDIM + d) * SEQ + s0]) = pk;
                } else {
                    unsigned short* dst = (which == 0) ? Qb : Kb;
                    float scale = (which == 0) ? 0.125f : 1.0f;
#pragma unroll
                    for (int r2 = 0; r2 < 4; ++r2) {
                        dst[((size_t)(bi * NHEAD + head) * SEQ + (s0 + r2)) * HDIM + d] =
                            f2bf((a[4 * g + r2] + bvv) * scale);
                    }
                }
            }
        }
    }
}

// ---- attention v4b (unchanged): swapped-QK^T 32x32 MFMA, in-register softmax ----
__global__ __launch_bounds__(256, 3) void attn_kernel(const unsigned short* __restrict__ Qb,
                                                      const unsigned short* __restrict__ Kb,
                                                      const unsigned short* __restrict__ VTb,
                                                      const float* __restrict__ mask,
                                                      float* __restrict__ out) {
    __shared__ float lds_ctx[2][32][64];   // 16 KB
    __shared__ float lds_den[2][32];       // 256 B

    const int tid = threadIdx.x;
    const int w = tid >> 6;
    const int l = tid & 63;
    const int lq = l & 31;
    const int h5 = l >> 5;
    const int qg = w & 1;
    const int kh = w >> 1;

    const int id = blockIdx.x;   // 0..767
    const int hh = id % 96;      // same XCD for all qb of a head (96 % 8 == 0)
    const int qb = id / 96;
    const int b = hh / 12;
    const int hd = hh % 12;

    const size_t headoff = ((size_t)b * NHEAD + hd) * SEQ * HDIM;
    const size_t vtoff   = headoff;
    const int q0 = qb * 64 + qg * 32;
    const float4* mask4 = (const float4*)mask;

    bf16x8 qf[4];
#pragma unroll
    for (int dc = 0; dc < 4; ++dc)
        qf[dc] = *reinterpret_cast<const bf16x8*>(
            &Qb[headoff + (size_t)(q0 + lq) * HDIM + dc * 16 + h5 * 8]);

    f32x16 ctx0 = {};
    f32x16 ctx1 = {};
    float den = 0.f;

#pragma unroll 1
    for (int kb = 0; kb < 8; ++kb) {
        const int k0 = kh * 256 + kb * 32;

        bf16x8 kf[4];
#pragma unroll
        for (int dc = 0; dc < 4; ++dc)
            kf[dc] = *reinterpret_cast<const bf16x8*>(
                &Kb[headoff + (size_t)(k0 + lq) * HDIM + dc * 16 + h5 * 8]);

        f32x16 T = {};
#pragma unroll
        for (int dc = 0; dc < 4; ++dc)
            T = MFMA32(kf[dc], qf[dc], T);

        bf16x8 vf00 = *reinterpret_cast<const bf16x8*>(&VTb[vtoff + (size_t)(lq) * SEQ + k0 + h5 * 8]);
        bf16x8 vf10 = *reinterpret_cast<const bf16x8*>(&VTb[vtoff + (size_t)(lq) * SEQ + k0 + 16 + h5 * 8]);
        bf16x8 vf01 = *reinterpret_cast<const bf16x8*>(&VTb[vtoff + (size_t)(32 + lq) * SEQ + k0 + h5 * 8]);
        bf16x8 vf11 = *reinterpret_cast<const bf16x8*>(&VTb[vtoff + (size_t)(32 + lq) * SEQ + k0 + 16 + h5 * 8]);

        float4 mv[4];
#pragma unroll
        for (int g = 0; g < 4; ++g)
            mv[g] = mask4[b * 128 + (k0 >> 2) + 2 * g + h5];

        float p[16];
#pragma unroll
        for (int r = 0; r < 16; ++r) {
            float mval = (r & 3) == 0 ? mv[r >> 2].x : ((r & 3) == 1 ? mv[r >> 2].y
                       : ((r & 3) == 2 ? mv[r >> 2].z : mv[r >> 2].w));
            p[r] = __expf(T[r] + mval);
            den += p[r];
        }

        bf16x8 pa[2];
#pragma unroll
        for (int c = 0; c < 2; ++c) {
            int base = c * 8;
            unsigned int lo01 = cvtpk_bf16(p[base + 0], p[base + 1]);
            unsigned int lo23 = cvtpk_bf16(p[base + 2], p[base + 3]);
            unsigned int hi01 = cvtpk_bf16(p[base + 4], p[base + 5]);
            unsigned int hi23 = cvtpk_bf16(p[base + 6], p[base + 7]);
            u32x2 s1 = __builtin_amdgcn_permlane32_swap(lo01, hi01, false, false);  // {w0, w2}
            u32x2 s2 = __builtin_amdgcn_permlane32_swap(lo23, hi23, false, false);  // {w1, w3}
            u32x4 words = {s1[0], s2[0], s1[1], s2[1]};
            pa[c] = __builtin_bit_cast(bf16x8, words);
        }

        ctx0 = MFMA32(pa[0], vf00, ctx0);
        ctx0 = MFMA32(pa[1], vf10, ctx0);
        ctx1 = MFMA32(pa[0], vf01, ctx1);
        ctx1 = MFMA32(pa[1], vf11, ctx1);
    }

    float den_full = den + __shfl_xor(den, 32);

    if (kh == 1) {
        if (l < 32) lds_den[qg][l] = den_full;
#pragma unroll
        for (int r = 0; r < 16; ++r) {
            int qr = (r & 3) + 8 * (r >> 2) + 4 * h5;
            lds_ctx[qg][qr][lq] = ctx0[r];
            lds_ctx[qg][qr][32 + lq] = ctx1[r];
        }
    }
    __syncthreads();
    if (kh == 0) {
        float den_tot = den_full + lds_den[qg][lq];
#pragma unroll
        for (int r = 0; r < 16; ++r) {
            int qr = (r & 3) + 8 * (r >> 2) + 4 * h5;
            float dn = 1.0f / __shfl(den_tot, qr);
            size_t rowoff = ((size_t)b * SEQ + q0 + qr) * HID + hd * HDIM;
            out[rowoff + lq]      = (ctx0[r] + lds_ctx[qg][qr][lq]) * dn;
            out[rowoff + 32 + lq] = (ctx1[r] + lds_ctx[qg][qr][32 + lq]) * dn;
        }
    }
}

extern "C" void kernel_launch(void* const* d_in, const int* in_sizes, int n_in,
                              void* d_out, int out_size, void* d_ws, size_t ws_size,
                              hipStream_t stream) {
    const float* hs   = (const float*)d_in[0];
    const float* mask = (const float*)d_in[1];
    const float* Wq   = (const float*)d_in[2];
    const float* bq   = (const float*)d_in[3];
    const float* Wk   = (const float*)d_in[4];
    const float* bk   = (const float*)d_in[5];
    const float* Wv   = (const float*)d_in[6];
    const float* bv   = (const float*)d_in[7];
    float* out = (float*)d_out;

    char* ws = (char*)d_ws;
    unsigned short* hsb = (unsigned short*)(ws);           // 128x48 frags = 6291456 B
    unsigned short* wb  = (unsigned short*)(ws + 6291456); // 72x48 frags = 3538944 B
    unsigned short* Qb  = (unsigned short*)(ws + 9830400);
    unsigned short* Kb  = (unsigned short*)(ws + 16121856);
    unsigned short* VTb = (unsigned short*)(ws + 22413312);

    // 393216 hs-chunks + 221184 w-chunks = 614400 = 2400 * 256
    cvt_all_kernel<<<2400, 256, 0, stream>>>((const float4*)hs, (const float4*)Wq,
                                             (const float4*)Wk, (const float4*)Wv,
                                             hsb, wb);
    qkv_gemm_kernel<<<2304, 64, 0, stream>>>(hsb, wb, bq, bk, bv, Qb, Kb, VTb);
    attn_kernel<<<768, 256, 0, stream>>>(Qb, Kb, VTb, mask, out);
}

// Round 10
// 79.024 us; speedup vs baseline: 1.0419x; 1.0419x over previous
//
#include <hip/hip_runtime.h>
#include <hip/hip_bf16.h>

typedef __bf16 bf16x8 __attribute__((ext_vector_type(8)));
typedef float f32x4 __attribute__((ext_vector_type(4)));
typedef float f32x16 __attribute__((ext_vector_type(16)));
typedef unsigned int u32x2 __attribute__((ext_vector_type(2)));
typedef unsigned int u32x4 __attribute__((ext_vector_type(4)));
typedef unsigned short us8 __attribute__((ext_vector_type(8)));

#define MFMA32(a, b, c) __builtin_amdgcn_mfma_f32_32x32x16_bf16((a), (b), (c), 0, 0, 0)

// ---- constants ----
#define BATCH 8
#define SEQ 512
#define HID 768
#define NHEAD 12
#define HDIM 64

__device__ __forceinline__ unsigned short f2bf(float f) {
    unsigned int u = __float_as_uint(f);
    u += 0x7fffu + ((u >> 16) & 1u);
    return (unsigned short)(u >> 16);
}

__device__ __forceinline__ unsigned int cvtpk_bf16(float lo, float hi) {
    unsigned int r;
    asm("v_cvt_pk_bf16_f32 %0, %1, %2" : "=v"(r) : "v"(lo), "v"(hi));
    return r;
}

// ---- fused fp32 -> bf16 convert INTO MFMA-FRAGMENT-TILED layout (unchanged) ----
// frag(t, kt) = 1024 contiguous bytes: lane l's 8 bf16 at l*16B covering
// (row = l&31, k = kt*16 + (l>>5)*8 + j).
__global__ __launch_bounds__(256) void cvt_all_kernel(const float4* __restrict__ hs,
                                                      const float4* __restrict__ Wq,
                                                      const float4* __restrict__ Wk,
                                                      const float4* __restrict__ Wv,
                                                      unsigned short* __restrict__ hsb,
                                                      unsigned short* __restrict__ wb) {
    int i = blockIdx.x * 256 + threadIdx.x;   // chunk-of-8-floats index
    float4 v0, v1;
    unsigned short* dst;
    size_t uidx;
    if (i < 393216) {                         // hidden: 4096 rows x 96 chunks
        int m = i / 96, cc = i - (i / 96) * 96;
        v0 = hs[2 * i];
        v1 = hs[2 * i + 1];
        uidx = ((size_t)((m >> 5) * 48 + (cc >> 1))) * 512 + (((cc & 1) << 5) + (m & 31)) * 8;
        dst = hsb;
    } else {                                  // weights: 3 x 768 rows x 96 chunks
        int j = i - 393216;
        int which = j / 73728;
        int jj = j - which * 73728;
        int n = jj / 96, cc = jj - (jj / 96) * 96;
        const float4* src = (which == 0) ? Wq : ((which == 1) ? Wk : Wv);
        v0 = src[2 * jj];
        v1 = src[2 * jj + 1];
        int nt = which * 24 + (n >> 5);
        uidx = ((size_t)(nt * 48 + (cc >> 1))) * 512 + (((cc & 1) << 5) + (n & 31)) * 8;
        dst = wb;
    }
    us8 o;
    o[0] = f2bf(v0.x); o[1] = f2bf(v0.y); o[2] = f2bf(v0.z); o[3] = f2bf(v0.w);
    o[4] = f2bf(v1.x); o[5] = f2bf(v1.y); o[6] = f2bf(v1.z); o[7] = f2bf(v1.w);
    *reinterpret_cast<us8*>(dst + uidx) = o;
}

// ---- fused QKV GEMM v6: R9 loop, but 4 waves/block sharing fragments via L1 ----
// Block = 2x2 waves over a 128x128 tile; wave (wr,wc) owns 64x64 via 2x2 MFMA32.
// Row-waves share the A-fragment pair, column-waves share B -> second reader
// hits L1, halving L2-side traffic (452 -> 226 MB). No LDS, no barriers.
__global__ __launch_bounds__(256) void qkv_gemm_kernel(const unsigned short* __restrict__ hsb,
                                                       const unsigned short* __restrict__ wb,
                                                       const float* __restrict__ bq,
                                                       const float* __restrict__ bk,
                                                       const float* __restrict__ bv,
                                                       unsigned short* __restrict__ Qb,
                                                       unsigned short* __restrict__ Kb,
                                                       unsigned short* __restrict__ VTb) {
    const int tid = threadIdx.x;
    const int w = tid >> 6;
    const int l = tid & 63;
    const int lq = l & 31, h5 = l >> 5;
    const int wr = w >> 1, wc = w & 1;

    // XCD-aware remap: xcd = id&7 owns an 8Mx9N rectangle of 128x128 tiles (3.3MB < L2)
    const int id = blockIdx.x;            // 0..575
    const int xcd = id & 7, j = id >> 3;  // j in [0,72) = 8 x 9
    const int tm = (xcd >> 1) * 8 + j / 9;   // 0..31
    const int tn = (xcd & 1) * 9 + j % 9;    // 0..17

    const int fa0 = tm * 4 + wr * 2;      // A frag-rows fa0, fa0+1 (shared with wc-sibling)
    const int fb0 = tn * 4 + wc * 2;      // B frag-cols fb0, fb0+1 (shared with wr-sibling)

    const unsigned short* pa0 = hsb + (size_t)fa0 * 48 * 512 + l * 8;
    const unsigned short* pa1 = pa0 + 48 * 512;
    const unsigned short* pb0 = wb + (size_t)fb0 * 48 * 512 + l * 8;
    const unsigned short* pb1 = pb0 + 48 * 512;

    f32x16 acc00 = {}, acc01 = {}, acc10 = {}, acc11 = {};

#pragma unroll 4
    for (int kt = 0; kt < 48; ++kt) {
        bf16x8 a0 = *reinterpret_cast<const bf16x8*>(pa0 + kt * 512);
        bf16x8 a1 = *reinterpret_cast<const bf16x8*>(pa1 + kt * 512);
        bf16x8 b0 = *reinterpret_cast<const bf16x8*>(pb0 + kt * 512);
        bf16x8 b1 = *reinterpret_cast<const bf16x8*>(pb1 + kt * 512);
        acc00 = MFMA32(a0, b0, acc00);
        acc01 = MFMA32(a0, b1, acc01);
        acc10 = MFMA32(a1, b0, acc10);
        acc11 = MFMA32(a1, b1, acc11);
    }

    // epilogue: C/D col = lq, row = (r&3) + 8*(r>>2) + 4*h5  (r in [0,16))
    f32x16 accs[2][2] = {{acc00, acc01}, {acc10, acc11}};
#pragma unroll
    for (int ni = 0; ni < 2; ++ni) {
        int col = (fb0 + ni) * 32 + lq;           // 0..2303
        int which = col / HID;                    // 0=Q 1=K 2=V
        int oo = col - which * HID;
        int head = oo >> 6, d = oo & 63;
        const float* bias = (which == 0) ? bq : ((which == 1) ? bk : bv);
        float bvv = bias[oo];
#pragma unroll
        for (int mi = 0; mi < 2; ++mi) {
            f32x16 a = accs[mi][ni];
#pragma unroll
            for (int g = 0; g < 4; ++g) {
                int row0 = (fa0 + mi) * 32 + 8 * g + 4 * h5;   // 4-aligned
                int bi = row0 >> 9;
                int s0 = row0 & 511;
                if (which == 2) {
                    ushort4 pk;
                    pk.x = f2bf(a[4 * g + 0] + bvv);
                    pk.y = f2bf(a[4 * g + 1] + bvv);
                    pk.z = f2bf(a[4 * g + 2] + bvv);
                    pk.w = f2bf(a[4 * g + 3] + bvv);
                    *reinterpret_cast<ushort4*>(
                        &VTb[((size_t)(bi * NHEAD + head) * HDIM + d) * SEQ + s0]) = pk;
                } else {
                    unsigned short* dst = (which == 0) ? Qb : Kb;
                    float scale = (which == 0) ? 0.125f : 1.0f;
#pragma unroll
                    for (int r2 = 0; r2 < 4; ++r2) {
                        dst[((size_t)(bi * NHEAD + head) * SEQ + (s0 + r2)) * HDIM + d] =
                            f2bf((a[4 * g + r2] + bvv) * scale);
                    }
                }
            }
        }
    }
}

// ---- attention v4b (unchanged): swapped-QK^T 32x32 MFMA, in-register softmax ----
__global__ __launch_bounds__(256, 3) void attn_kernel(const unsigned short* __restrict__ Qb,
                                                      const unsigned short* __restrict__ Kb,
                                                      const unsigned short* __restrict__ VTb,
                                                      const float* __restrict__ mask,
                                                      float* __restrict__ out) {
    __shared__ float lds_ctx[2][32][64];   // 16 KB
    __shared__ float lds_den[2][32];       // 256 B

    const int tid = threadIdx.x;
    const int w = tid >> 6;
    const int l = tid & 63;
    const int lq = l & 31;
    const int h5 = l >> 5;
    const int qg = w & 1;
    const int kh = w >> 1;

    const int id = blockIdx.x;   // 0..767
    const int hh = id % 96;      // same XCD for all qb of a head (96 % 8 == 0)
    const int qb = id / 96;
    const int b = hh / 12;
    const int hd = hh % 12;

    const size_t headoff = ((size_t)b * NHEAD + hd) * SEQ * HDIM;
    const size_t vtoff   = headoff;
    const int q0 = qb * 64 + qg * 32;
    const float4* mask4 = (const float4*)mask;

    bf16x8 qf[4];
#pragma unroll
    for (int dc = 0; dc < 4; ++dc)
        qf[dc] = *reinterpret_cast<const bf16x8*>(
            &Qb[headoff + (size_t)(q0 + lq) * HDIM + dc * 16 + h5 * 8]);

    f32x16 ctx0 = {};
    f32x16 ctx1 = {};
    float den = 0.f;

#pragma unroll 1
    for (int kb = 0; kb < 8; ++kb) {
        const int k0 = kh * 256 + kb * 32;

        bf16x8 kf[4];
#pragma unroll
        for (int dc = 0; dc < 4; ++dc)
            kf[dc] = *reinterpret_cast<const bf16x8*>(
                &Kb[headoff + (size_t)(k0 + lq) * HDIM + dc * 16 + h5 * 8]);

        f32x16 T = {};
#pragma unroll
        for (int dc = 0; dc < 4; ++dc)
            T = MFMA32(kf[dc], qf[dc], T);

        bf16x8 vf00 = *reinterpret_cast<const bf16x8*>(&VTb[vtoff + (size_t)(lq) * SEQ + k0 + h5 * 8]);
        bf16x8 vf10 = *reinterpret_cast<const bf16x8*>(&VTb[vtoff + (size_t)(lq) * SEQ + k0 + 16 + h5 * 8]);
        bf16x8 vf01 = *reinterpret_cast<const bf16x8*>(&VTb[vtoff + (size_t)(32 + lq) * SEQ + k0 + h5 * 8]);
        bf16x8 vf11 = *reinterpret_cast<const bf16x8*>(&VTb[vtoff + (size_t)(32 + lq) * SEQ + k0 + 16 + h5 * 8]);

        float4 mv[4];
#pragma unroll
        for (int g = 0; g < 4; ++g)
            mv[g] = mask4[b * 128 + (k0 >> 2) + 2 * g + h5];

        float p[16];
#pragma unroll
        for (int r = 0; r < 16; ++r) {
            float mval = (r & 3) == 0 ? mv[r >> 2].x : ((r & 3) == 1 ? mv[r >> 2].y
                       : ((r & 3) == 2 ? mv[r >> 2].z : mv[r >> 2].w));
            p[r] = __expf(T[r] + mval);
            den += p[r];
        }

        bf16x8 pa[2];
#pragma unroll
        for (int c = 0; c < 2; ++c) {
            int base = c * 8;
            unsigned int lo01 = cvtpk_bf16(p[base + 0], p[base + 1]);
            unsigned int lo23 = cvtpk_bf16(p[base + 2], p[base + 3]);
            unsigned int hi01 = cvtpk_bf16(p[base + 4], p[base + 5]);
            unsigned int hi23 = cvtpk_bf16(p[base + 6], p[base + 7]);
            u32x2 s1 = __builtin_amdgcn_permlane32_swap(lo01, hi01, false, false);  // {w0, w2}
            u32x2 s2 = __builtin_amdgcn_permlane32_swap(lo23, hi23, false, false);  // {w1, w3}
            u32x4 words = {s1[0], s2[0], s1[1], s2[1]};
            pa[c] = __builtin_bit_cast(bf16x8, words);
        }

        ctx0 = MFMA32(pa[0], vf00, ctx0);
        ctx0 = MFMA32(pa[1], vf10, ctx0);
        ctx1 = MFMA32(pa[0], vf01, ctx1);
        ctx1 = MFMA32(pa[1], vf11, ctx1);
    }

    float den_full = den + __shfl_xor(den, 32);

    if (kh == 1) {
        if (l < 32) lds_den[qg][l] = den_full;
#pragma unroll
        for (int r = 0; r < 16; ++r) {
            int qr = (r & 3) + 8 * (r >> 2) + 4 * h5;
            lds_ctx[qg][qr][lq] = ctx0[r];
            lds_ctx[qg][qr][32 + lq] = ctx1[r];
        }
    }
    __syncthreads();
    if (kh == 0) {
        float den_tot = den_full + lds_den[qg][lq];
#pragma unroll
        for (int r = 0; r < 16; ++r) {
            int qr = (r & 3) + 8 * (r >> 2) + 4 * h5;
            float dn = 1.0f / __shfl(den_tot, qr);
            size_t rowoff = ((size_t)b * SEQ + q0 + qr) * HID + hd * HDIM;
            out[rowoff + lq]      = (ctx0[r] + lds_ctx[qg][qr][lq]) * dn;
            out[rowoff + 32 + lq] = (ctx1[r] + lds_ctx[qg][qr][32 + lq]) * dn;
        }
    }
}

extern "C" void kernel_launch(void* const* d_in, const int* in_sizes, int n_in,
                              void* d_out, int out_size, void* d_ws, size_t ws_size,
                              hipStream_t stream) {
    const float* hs   = (const float*)d_in[0];
    const float* mask = (const float*)d_in[1];
    const float* Wq   = (const float*)d_in[2];
    const float* bq   = (const float*)d_in[3];
    const float* Wk   = (const float*)d_in[4];
    const float* bk   = (const float*)d_in[5];
    const float* Wv   = (const float*)d_in[6];
    const float* bv   = (const float*)d_in[7];
    float* out = (float*)d_out;

    char* ws = (char*)d_ws;
    unsigned short* hsb = (unsigned short*)(ws);           // 128x48 frags = 6291456 B
    unsigned short* wb  = (unsigned short*)(ws + 6291456); // 72x48 frags = 3538944 B
    unsigned short* Qb  = (unsigned short*)(ws + 9830400);
    unsigned short* Kb  = (unsigned short*)(ws + 16121856);
    unsigned short* VTb = (unsigned short*)(ws + 22413312);

    // 393216 hs-chunks + 221184 w-chunks = 614400 = 2400 * 256
    cvt_all_kernel<<<2400, 256, 0, stream>>>((const float4*)hs, (const float4*)Wq,
                                             (const float4*)Wk, (const float4*)Wv,
                                             hsb, wb);
    qkv_gemm_kernel<<<576, 256, 0, stream>>>(hsb, wb, bq, bk, bv, Qb, Kb, VTb);
    attn_kernel<<<768, 256, 0, stream>>>(Qb, Kb, VTb, mask, out);
}

// Round 11
// 72.767 us; speedup vs baseline: 1.1315x; 1.0860x over previous
//
#include <hip/hip_runtime.h>
#include <hip/hip_bf16.h>

typedef __bf16 bf16x8 __attribute__((ext_vector_type(8)));
typedef float f32x4 __attribute__((ext_vector_type(4)));
typedef float f32x16 __attribute__((ext_vector_type(16)));
typedef unsigned int u32x2 __attribute__((ext_vector_type(2)));
typedef unsigned int u32x4 __attribute__((ext_vector_type(4)));
typedef unsigned short us8 __attribute__((ext_vector_type(8)));

#define MFMA32(a, b, c) __builtin_amdgcn_mfma_f32_32x32x16_bf16((a), (b), (c), 0, 0, 0)

// ---- constants ----
#define BATCH 8
#define SEQ 512
#define HID 768
#define NHEAD 12
#define HDIM 64

__device__ __forceinline__ unsigned short f2bf(float f) {
    unsigned int u = __float_as_uint(f);
    u += 0x7fffu + ((u >> 16) & 1u);
    return (unsigned short)(u >> 16);
}

__device__ __forceinline__ unsigned int cvtpk_bf16(float lo, float hi) {
    unsigned int r;
    asm("v_cvt_pk_bf16_f32 %0, %1, %2" : "=v"(r) : "v"(lo), "v"(hi));
    return r;
}

// ---- fused fp32 -> bf16 convert INTO MFMA-FRAGMENT-TILED layout (unchanged) ----
// frag(t, kt) = 1024 contiguous bytes: lane l's 8 bf16 at l*16B covering
// (row = l&31, k = kt*16 + (l>>5)*8 + j).
__global__ __launch_bounds__(256) void cvt_all_kernel(const float4* __restrict__ hs,
                                                      const float4* __restrict__ Wq,
                                                      const float4* __restrict__ Wk,
                                                      const float4* __restrict__ Wv,
                                                      unsigned short* __restrict__ hsb,
                                                      unsigned short* __restrict__ wb) {
    int i = blockIdx.x * 256 + threadIdx.x;   // chunk-of-8-floats index
    float4 v0, v1;
    unsigned short* dst;
    size_t uidx;
    if (i < 393216) {                         // hidden: 4096 rows x 96 chunks
        int m = i / 96, cc = i - (i / 96) * 96;
        v0 = hs[2 * i];
        v1 = hs[2 * i + 1];
        uidx = ((size_t)((m >> 5) * 48 + (cc >> 1))) * 512 + (((cc & 1) << 5) + (m & 31)) * 8;
        dst = hsb;
    } else {                                  // weights: 3 x 768 rows x 96 chunks
        int j = i - 393216;
        int which = j / 73728;
        int jj = j - which * 73728;
        int n = jj / 96, cc = jj - (jj / 96) * 96;
        const float4* src = (which == 0) ? Wq : ((which == 1) ? Wk : Wv);
        v0 = src[2 * jj];
        v1 = src[2 * jj + 1];
        int nt = which * 24 + (n >> 5);
        uidx = ((size_t)(nt * 48 + (cc >> 1))) * 512 + (((cc & 1) << 5) + (n & 31)) * 8;
        dst = wb;
    }
    us8 o;
    o[0] = f2bf(v0.x); o[1] = f2bf(v0.y); o[2] = f2bf(v0.z); o[3] = f2bf(v0.w);
    o[4] = f2bf(v1.x); o[5] = f2bf(v1.y); o[6] = f2bf(v1.z); o[7] = f2bf(v1.w);
    *reinterpret_cast<us8*>(dst + uidx) = o;
}

// ---- fused QKV GEMM v7: split-K=2 for occupancy + shorter serial chains ----
// 576 blocks x 512 threads. Wave (quad, kh): quadrant of the 128x128 tile,
// K-half kh (24 kt). 4608 waves (2x R10), per-wave chain halved. kh=1 accs
// merged into kh=0 via value-major LDS (f32, exact); kh=0 runs the epilogue.
__global__ __launch_bounds__(512) void qkv_gemm_kernel(const unsigned short* __restrict__ hsb,
                                                       const unsigned short* __restrict__ wb,
                                                       const float* __restrict__ bq,
                                                       const float* __restrict__ bk,
                                                       const float* __restrict__ bv,
                                                       unsigned short* __restrict__ Qb,
                                                       unsigned short* __restrict__ Kb,
                                                       unsigned short* __restrict__ VTb) {
    __shared__ float lds_part[4][64][64];   // [quad][value][lane] = 64 KB

    const int tid = threadIdx.x;
    const int w = tid >> 6;               // 0..7
    const int l = tid & 63;
    const int lq = l & 31, h5 = l >> 5;
    const int quad = w & 3;               // 2x2 quadrant of the 128x128 tile
    const int kh = w >> 2;                // K-half: 0 -> kt 0..23, 1 -> kt 24..47
    const int wr = quad >> 1, wc = quad & 1;

    // XCD-aware remap: xcd = id&7 owns an 8Mx9N rectangle of 128x128 tiles
    const int id = blockIdx.x;            // 0..575
    const int xcd = id & 7, j = id >> 3;  // j in [0,72) = 8 x 9
    const int tm = (xcd >> 1) * 8 + j / 9;   // 0..31
    const int tn = (xcd & 1) * 9 + j % 9;    // 0..17

    const int fa0 = tm * 4 + wr * 2;      // A frag-rows fa0, fa0+1
    const int fb0 = tn * 4 + wc * 2;      // B frag-cols fb0, fb0+1

    const unsigned short* pa0 = hsb + (size_t)fa0 * 48 * 512 + kh * 24 * 512 + l * 8;
    const unsigned short* pa1 = pa0 + 48 * 512;
    const unsigned short* pb0 = wb + (size_t)fb0 * 48 * 512 + kh * 24 * 512 + l * 8;
    const unsigned short* pb1 = pb0 + 48 * 512;

    f32x16 acc00 = {}, acc01 = {}, acc10 = {}, acc11 = {};

#pragma unroll 4
    for (int kt = 0; kt < 24; ++kt) {
        bf16x8 a0 = *reinterpret_cast<const bf16x8*>(pa0 + kt * 512);
        bf16x8 a1 = *reinterpret_cast<const bf16x8*>(pa1 + kt * 512);
        bf16x8 b0 = *reinterpret_cast<const bf16x8*>(pb0 + kt * 512);
        bf16x8 b1 = *reinterpret_cast<const bf16x8*>(pb1 + kt * 512);
        acc00 = MFMA32(a0, b0, acc00);
        acc01 = MFMA32(a0, b1, acc01);
        acc10 = MFMA32(a1, b0, acc10);
        acc11 = MFMA32(a1, b1, acc11);
    }

    f32x16 accs[2][2] = {{acc00, acc01}, {acc10, acc11}};

    // ---- split-K combine: kh=1 stores value-major (lane-contiguous, conflict-free) ----
    if (kh == 1) {
#pragma unroll
        for (int mi = 0; mi < 2; ++mi)
#pragma unroll
            for (int ni = 0; ni < 2; ++ni)
#pragma unroll
                for (int r = 0; r < 16; ++r)
                    lds_part[quad][(mi * 2 + ni) * 16 + r][l] = accs[mi][ni][r];
    }
    __syncthreads();
    if (kh == 1) return;

#pragma unroll
    for (int mi = 0; mi < 2; ++mi)
#pragma unroll
        for (int ni = 0; ni < 2; ++ni)
#pragma unroll
            for (int r = 0; r < 16; ++r)
                accs[mi][ni][r] += lds_part[quad][(mi * 2 + ni) * 16 + r][l];

    // epilogue: C/D col = lq, row = (r&3) + 8*(r>>2) + 4*h5  (r in [0,16))
#pragma unroll
    for (int ni = 0; ni < 2; ++ni) {
        int col = (fb0 + ni) * 32 + lq;           // 0..2303
        int which = col / HID;                    // 0=Q 1=K 2=V
        int oo = col - which * HID;
        int head = oo >> 6, d = oo & 63;
        const float* bias = (which == 0) ? bq : ((which == 1) ? bk : bv);
        float bvv = bias[oo];
#pragma unroll
        for (int mi = 0; mi < 2; ++mi) {
            f32x16 a = accs[mi][ni];
#pragma unroll
            for (int g = 0; g < 4; ++g) {
                int row0 = (fa0 + mi) * 32 + 8 * g + 4 * h5;   // 4-aligned
                int bi = row0 >> 9;
                int s0 = row0 & 511;
                if (which == 2) {
                    ushort4 pk;
                    pk.x = f2bf(a[4 * g + 0] + bvv);
                    pk.y = f2bf(a[4 * g + 1] + bvv);
                    pk.z = f2bf(a[4 * g + 2] + bvv);
                    pk.w = f2bf(a[4 * g + 3] + bvv);
                    *reinterpret_cast<ushort4*>(
                        &VTb[((size_t)(bi * NHEAD + head) * HDIM + d) * SEQ + s0]) = pk;
                } else {
                    unsigned short* dst = (which == 0) ? Qb : Kb;
                    float scale = (which == 0) ? 0.125f : 1.0f;
#pragma unroll
                    for (int r2 = 0; r2 < 4; ++r2) {
                        dst[((size_t)(bi * NHEAD + head) * SEQ + (s0 + r2)) * HDIM + d] =
                            f2bf((a[4 * g + r2] + bvv) * scale);
                    }
                }
            }
        }
    }
}

// ---- attention v4b (unchanged): swapped-QK^T 32x32 MFMA, in-register softmax ----
__global__ __launch_bounds__(256, 3) void attn_kernel(const unsigned short* __restrict__ Qb,
                                                      const unsigned short* __restrict__ Kb,
                                                      const unsigned short* __restrict__ VTb,
                                                      const float* __restrict__ mask,
                                                      float* __restrict__ out) {
    __shared__ float lds_ctx[2][32][64];   // 16 KB
    __shared__ float lds_den[2][32];       // 256 B

    const int tid = threadIdx.x;
    const int w = tid >> 6;
    const int l = tid & 63;
    const int lq = l & 31;
    const int h5 = l >> 5;
    const int qg = w & 1;
    const int kh = w >> 1;

    const int id = blockIdx.x;   // 0..767
    const int hh = id % 96;      // same XCD for all qb of a head (96 % 8 == 0)
    const int qb = id / 96;
    const int b = hh / 12;
    const int hd = hh % 12;

    const size_t headoff = ((size_t)b * NHEAD + hd) * SEQ * HDIM;
    const size_t vtoff   = headoff;
    const int q0 = qb * 64 + qg * 32;
    const float4* mask4 = (const float4*)mask;

    bf16x8 qf[4];
#pragma unroll
    for (int dc = 0; dc < 4; ++dc)
        qf[dc] = *reinterpret_cast<const bf16x8*>(
            &Qb[headoff + (size_t)(q0 + lq) * HDIM + dc * 16 + h5 * 8]);

    f32x16 ctx0 = {};
    f32x16 ctx1 = {};
    float den = 0.f;

#pragma unroll 1
    for (int kb = 0; kb < 8; ++kb) {
        const int k0 = kh * 256 + kb * 32;

        bf16x8 kf[4];
#pragma unroll
        for (int dc = 0; dc < 4; ++dc)
            kf[dc] = *reinterpret_cast<const bf16x8*>(
                &Kb[headoff + (size_t)(k0 + lq) * HDIM + dc * 16 + h5 * 8]);

        f32x16 T = {};
#pragma unroll
        for (int dc = 0; dc < 4; ++dc)
            T = MFMA32(kf[dc], qf[dc], T);

        bf16x8 vf00 = *reinterpret_cast<const bf16x8*>(&VTb[vtoff + (size_t)(lq) * SEQ + k0 + h5 * 8]);
        bf16x8 vf10 = *reinterpret_cast<const bf16x8*>(&VTb[vtoff + (size_t)(lq) * SEQ + k0 + 16 + h5 * 8]);
        bf16x8 vf01 = *reinterpret_cast<const bf16x8*>(&VTb[vtoff + (size_t)(32 + lq) * SEQ + k0 + h5 * 8]);
        bf16x8 vf11 = *reinterpret_cast<const bf16x8*>(&VTb[vtoff + (size_t)(32 + lq) * SEQ + k0 + 16 + h5 * 8]);

        float4 mv[4];
#pragma unroll
        for (int g = 0; g < 4; ++g)
            mv[g] = mask4[b * 128 + (k0 >> 2) + 2 * g + h5];

        float p[16];
#pragma unroll
        for (int r = 0; r < 16; ++r) {
            float mval = (r & 3) == 0 ? mv[r >> 2].x : ((r & 3) == 1 ? mv[r >> 2].y
                       : ((r & 3) == 2 ? mv[r >> 2].z : mv[r >> 2].w));
            p[r] = __expf(T[r] + mval);
            den += p[r];
        }

        bf16x8 pa[2];
#pragma unroll
        for (int c = 0; c < 2; ++c) {
            int base = c * 8;
            unsigned int lo01 = cvtpk_bf16(p[base + 0], p[base + 1]);
            unsigned int lo23 = cvtpk_bf16(p[base + 2], p[base + 3]);
            unsigned int hi01 = cvtpk_bf16(p[base + 4], p[base + 5]);
            unsigned int hi23 = cvtpk_bf16(p[base + 6], p[base + 7]);
            u32x2 s1 = __builtin_amdgcn_permlane32_swap(lo01, hi01, false, false);  // {w0, w2}
            u32x2 s2 = __builtin_amdgcn_permlane32_swap(lo23, hi23, false, false);  // {w1, w3}
            u32x4 words = {s1[0], s2[0], s1[1], s2[1]};
            pa[c] = __builtin_bit_cast(bf16x8, words);
        }

        ctx0 = MFMA32(pa[0], vf00, ctx0);
        ctx0 = MFMA32(pa[1], vf10, ctx0);
        ctx1 = MFMA32(pa[0], vf01, ctx1);
        ctx1 = MFMA32(pa[1], vf11, ctx1);
    }

    float den_full = den + __shfl_xor(den, 32);

    if (kh == 1) {
        if (l < 32) lds_den[qg][l] = den_full;
#pragma unroll
        for (int r = 0; r < 16; ++r) {
            int qr = (r & 3) + 8 * (r >> 2) + 4 * h5;
            lds_ctx[qg][qr][lq] = ctx0[r];
            lds_ctx[qg][qr][32 + lq] = ctx1[r];
        }
    }
    __syncthreads();
    if (kh == 0) {
        float den_tot = den_full + lds_den[qg][lq];
#pragma unroll
        for (int r = 0; r < 16; ++r) {
            int qr = (r & 3) + 8 * (r >> 2) + 4 * h5;
            float dn = 1.0f / __shfl(den_tot, qr);
            size_t rowoff = ((size_t)b * SEQ + q0 + qr) * HID + hd * HDIM;
            out[rowoff + lq]      = (ctx0[r] + lds_ctx[qg][qr][lq]) * dn;
            out[rowoff + 32 + lq] = (ctx1[r] + lds_ctx[qg][qr][32 + lq]) * dn;
        }
    }
}

extern "C" void kernel_launch(void* const* d_in, const int* in_sizes, int n_in,
                              void* d_out, int out_size, void* d_ws, size_t ws_size,
                              hipStream_t stream) {
    const float* hs   = (const float*)d_in[0];
    const float* mask = (const float*)d_in[1];
    const float* Wq   = (const float*)d_in[2];
    const float* bq   = (const float*)d_in[3];
    const float* Wk   = (const float*)d_in[4];
    const float* bk   = (const float*)d_in[5];
    const float* Wv   = (const float*)d_in[6];
    const float* bv   = (const float*)d_in[7];
    float* out = (float*)d_out;

    char* ws = (char*)d_ws;
    unsigned short* hsb = (unsigned short*)(ws);           // 128x48 frags = 6291456 B
    unsigned short* wb  = (unsigned short*)(ws + 6291456); // 72x48 frags = 3538944 B
    unsigned short* Qb  = (unsigned short*)(ws + 9830400);
    unsigned short* Kb  = (unsigned short*)(ws + 16121856);
    unsigned short* VTb = (unsigned short*)(ws + 22413312);

    // 393216 hs-chunks + 221184 w-chunks = 614400 = 2400 * 256
    cvt_all_kernel<<<2400, 256, 0, stream>>>((const float4*)hs, (const float4*)Wq,
                                             (const float4*)Wk, (const float4*)Wv,
                                             hsb, wb);
    qkv_gemm_kernel<<<576, 512, 0, stream>>>(hsb, wb, bq, bk, bv, Qb, Kb, VTb);
    attn_kernel<<<768, 256, 0, stream>>>(Qb, Kb, VTb, mask, out);
}